// Round 6
// baseline (132.593 us; speedup 1.0000x reference)
//
#include <hip/hip_runtime.h>
#include <math.h>

namespace {
constexpr int kH = 512;
constexpr int kN = 64;
constexpr int kL = 4096;
constexpr int kM = 2048;    // L/2
constexpr int kThreads = 256;
constexpr int kFftThreads = 512;
constexpr float kPi = 3.14159265358979323846f;
}

__device__ __forceinline__ int lpad(int i) { return i + (i >> 4); }

__device__ __forceinline__ float rlane(float v, int lane) {
    return __uint_as_float(__builtin_amdgcn_readlane(__float_as_uint(v), (unsigned)lane));
}

// ===================== Kernel 1: spectrum =====================
// grid = 512 heads x 2 halves, 256 threads, 4 bins/thread.
// Per-(h,n) coefficients are computed ONCE per wave: lane n derives record n
// from the raw inputs (9 coalesced loads + ~45 VALU), keeps the 18 floats in
// VGPRs. The n-loop broadcasts each coefficient with v_readlane (uniform
// SGPR index) -- no LDS, no SMEM, no memory stalls in the hot loop.
//
// Math (s = 4t^2, t = tan(pi*l/L), D = m1*m2 with m = ar^2 + (2t -+ ai)^2):
//   s_r(l) += (a0 + a1*s)/D,  s_i(l) += t*(b0 + b1*s)/D per product term;
//   a0 = -2*C1*(vr*ar + vi*ai)        a1 = 2*(vi*ai - vr*ar)
//   b0 = -4*vr*(ar^2-ai^2) - 8*vi*ar*ai   b1 = -4*vr     [C1 = ar^2+ai^2]
//   k_f = (s00 - s01*s10/(1+s11)) * (1 + i*t)
// D kept in product form: polynomial-in-s form cancels catastrophically at
// resonances (ar^2 ~ 1e-7 vs ai^4 ~ 1e5).
__global__ __launch_bounds__(kThreads)
void s4_spectrum(const float* __restrict__ A_real,
                 const float* __restrict__ A_imag,
                 const float* __restrict__ Bv,
                 const float* __restrict__ Cv,
                 const float* __restrict__ Pv,
                 const float* __restrict__ inv_dt,
                 float2* __restrict__ Xg)
{
    const int h    = blockIdx.x >> 1;
    const int half = blockIdx.x & 1;
    const int tid  = threadIdx.x;
    const int lane = tid & 63;

    // ---- per-lane record (lane = n) ----
    float g0,g1,g2,g3,g4,g5,g6,g7,g8,g9,g10,g11,g12,g13,g14,g15,g16,g17;
    {
        const int idx = h * kN + lane;
        const float dt = expf(inv_dt[h]);
        const float ar = -expf(A_real[idx]) * dt;   // Re(A*dt) (negative)
        const float ai =  A_imag[idx] * dt;         // Im(A*dt)
        const float br = Bv[idx*2+0], bi = Bv[idx*2+1];
        const float cr = Cv[idx*2+0], ci = Cv[idx*2+1];
        const float pr = Pv[idx*2+0], pi = Pv[idx*2+1];
        const float v00r = (br*cr - bi*ci)*dt, v00i = (br*ci + bi*cr)*dt;  // B*C
        const float v01r = (br*pr + bi*pi)*dt, v01i = (bi*pr - br*pi)*dt;  // B*conj(P)
        const float v10r = (pr*cr - pi*ci)*dt, v10i = (pr*ci + pi*cr)*dt;  // P*C
        const float v11r = (pr*pr + pi*pi)*dt;                              // |P|^2
        const float ar2 = ar*ar;
        const float C1  = ar2 + ai*ai;
        const float dd  = ar2 - ai*ai;
        g0  = ai;  g1 = ar2;
        g2  = -2.f*C1*(v00r*ar + v00i*ai);   g3  = 2.f*(v00i*ai - v00r*ar);
        g4  = -4.f*v00r*dd - 8.f*v00i*ar*ai; g5  = -4.f*v00r;
        g6  = -2.f*C1*(v01r*ar + v01i*ai);   g7  = 2.f*(v01i*ai - v01r*ar);
        g8  = -4.f*v01r*dd - 8.f*v01i*ar*ai; g9  = -4.f*v01r;
        g10 = -2.f*C1*(v10r*ar + v10i*ai);   g11 = 2.f*(v10i*ai - v10r*ar);
        g12 = -4.f*v10r*dd - 8.f*v10i*ar*ai; g13 = -4.f*v10r;
        g14 = -2.f*C1*(v11r*ar);             g15 = -2.f*v11r*ar;
        g16 = -4.f*v11r*dd;                  g17 = -4.f*v11r;
    }

    const int lbase = half * 1024 + tid;
    float tv[4], t2v[4], sv[4];
    #pragma unroll
    for (int b = 0; b < 4; ++b) {
        const int l = lbase + 256 * b;
        float sn, cn;
        sincosf((float)l * (kPi / (float)kL), &sn, &cn);
        tv[b]  = sn / cn;            // tan(pi*l/L), finite for l <= 2047
        t2v[b] = 2.f * tv[b];
        sv[b]  = t2v[b] * t2v[b];    // s = 4t^2
    }

    float s00r[4] = {0,0,0,0}, s00i[4] = {0,0,0,0};
    float s01r[4] = {0,0,0,0}, s01i[4] = {0,0,0,0};
    float s10r[4] = {0,0,0,0}, s10i[4] = {0,0,0,0};
    float s11r[4] = {0,0,0,0}, s11i[4] = {0,0,0,0};

    #pragma unroll 2
    for (int n = 0; n < kN; ++n) {
        const float ai   = rlane(g0, n),  ar2  = rlane(g1, n);
        const float c00a = rlane(g2, n),  c00b = rlane(g3, n);
        const float c00c = rlane(g4, n),  c00d = rlane(g5, n);
        const float c01a = rlane(g6, n),  c01b = rlane(g7, n);
        const float c01c = rlane(g8, n),  c01d = rlane(g9, n);
        const float c10a = rlane(g10, n), c10b = rlane(g11, n);
        const float c10c = rlane(g12, n), c10d = rlane(g13, n);
        const float c11a = rlane(g14, n), c11b = rlane(g15, n);
        const float c11c = rlane(g16, n), c11d = rlane(g17, n);
        #pragma unroll
        for (int b = 0; b < 4; ++b) {
            const float w1 = t2v[b] - ai, w2 = t2v[b] + ai;
            const float m1 = fmaf(w1, w1, ar2), m2 = fmaf(w2, w2, ar2);
            const float invD = __builtin_amdgcn_rcpf(m1 * m2);
            const float sD = sv[b] * invD, tD = tv[b] * invD, stD = sv[b] * tD;
            s00r[b] = fmaf(c00a, invD, s00r[b]); s00r[b] = fmaf(c00b, sD,  s00r[b]);
            s00i[b] = fmaf(c00c, tD,   s00i[b]); s00i[b] = fmaf(c00d, stD, s00i[b]);
            s01r[b] = fmaf(c01a, invD, s01r[b]); s01r[b] = fmaf(c01b, sD,  s01r[b]);
            s01i[b] = fmaf(c01c, tD,   s01i[b]); s01i[b] = fmaf(c01d, stD, s01i[b]);
            s10r[b] = fmaf(c10a, invD, s10r[b]); s10r[b] = fmaf(c10b, sD,  s10r[b]);
            s10i[b] = fmaf(c10c, tD,   s10i[b]); s10i[b] = fmaf(c10d, stD, s10i[b]);
            s11r[b] = fmaf(c11a, invD, s11r[b]); s11r[b] = fmaf(c11b, sD,  s11r[b]);
            s11i[b] = fmaf(c11c, tD,   s11i[b]); s11i[b] = fmaf(c11d, stD, s11i[b]);
        }
    }

    #pragma unroll
    for (int b = 0; b < 4; ++b) {
        const int l = lbase + 256 * b;
        const float nr = s01r[b]*s10r[b] - s01i[b]*s10i[b];
        const float ni = s01r[b]*s10i[b] + s01i[b]*s10r[b];
        const float dr = 1.f + s11r[b], di = s11i[b];
        const float qd = __builtin_amdgcn_rcpf(fmaf(dr, dr, di*di));
        const float wr = (nr*dr + ni*di) * qd;
        const float wi = (ni*dr - nr*di) * qd;
        const float gr = s00r[b] - wr, gi = s00i[b] - wi;
        // k_f = g * (1 + i*t)
        Xg[h*kM + l] = make_float2(fmaf(-gi, tv[b], gr), fmaf(gr, tv[b], gi));
    }
}

// ===================== Kernel 2: irfft =====================
// One 512-thread block per head. Packed-real 2048-pt inverse complex DFT in
// LDS with index padding i+(i>>4) to break power-of-2 bank aliasing.
// Nyquist bin computed in-kernel: k_f[2048] = sum_n Re(B*C)*dt (real).
__global__ __launch_bounds__(kFftThreads)
void s4_ifft(const float* __restrict__ Bv,
             const float* __restrict__ Cv,
             const float* __restrict__ inv_dt,
             float* __restrict__ out)
{
    __shared__ float2 W2[kM + kM / 16];
    __shared__ float2 TW[kM / 2 + kM / 32];
    __shared__ float  XnyqR;

    const int h   = blockIdx.x;
    const int tid = threadIdx.x;
    const float2* Xg = (const float2*)(out + (size_t)h * kL);

    if (tid < kN) {   // wave 0: Nyquist bin
        const int idx = h * kN + tid;
        const float dt = expf(inv_dt[h]);
        const float br = Bv[idx*2+0], bi = Bv[idx*2+1];
        const float cr = Cv[idx*2+0], ci = Cv[idx*2+1];
        float vr = (br*cr - bi*ci) * dt;
        #pragma unroll
        for (int off = 32; off > 0; off >>= 1) vr += __shfl_down(vr, off, 64);
        if (tid == 0) XnyqR = vr;
    }
    for (int j = tid; j < kM / 2; j += kFftThreads) {
        float s, c;
        sincosf((2.0f * kPi / (float)kM) * (float)j, &s, &c);
        TW[lpad(j)] = make_float2(c, s);       // e^{+2pi i j / 2048}
    }
    __syncthreads();

    // build Z (bit-reversed) from global X:
    // E = (X[k]+conj(X[M-k]))/2 ; O = e^{+2pi i k/L}*(X[k]-conj(X[M-k]))/2
    // Z[k] = (Er-Oi, Ei+Or); Z[M-k] = (Er+Oi, Or-Ei)
    for (int k = tid; k <= kM / 2; k += kFftThreads) {
        const float2 Xa = Xg[k];
        const float2 Xb = (k == 0) ? make_float2(XnyqR, 0.0f) : Xg[kM - k];
        const float Er = 0.5f * (Xa.x + Xb.x);
        const float Ei = 0.5f * (Xa.y - Xb.y);
        const float Dr = 0.5f * (Xa.x - Xb.x);
        const float Di = 0.5f * (Xa.y + Xb.y);
        float s, c;
        sincosf((2.0f * kPi / (float)kL) * (float)k, &s, &c);
        const float Or = c * Dr - s * Di;
        const float Oi = c * Di + s * Dr;
        const int rk = (int)(__brev((unsigned)k) >> 21);          // 11-bit reversal
        W2[lpad(rk)] = make_float2(Er - Oi, Ei + Or);
        if (k != 0 && k != kM / 2) {
            const int rmk = (int)(__brev((unsigned)(kM - k)) >> 21);
            W2[lpad(rmk)] = make_float2(Er + Oi, Or - Ei);
        }
    }
    __syncthreads();

    for (int hs = 1; hs < kM; hs <<= 1) {
        const int tw_stride = (kM / 2) / hs;
        for (int j = tid; j < kM / 2; j += kFftThreads) {
            const int pos = j & (hs - 1);
            const int grp = j / hs;
            const int i0  = grp * 2 * hs + pos;
            const int i1  = i0 + hs;
            const float2 tw = TW[lpad(pos * tw_stride)];
            const float2 a = W2[lpad(i0)];
            const float2 b = W2[lpad(i1)];
            const float tr = tw.x * b.x - tw.y * b.y;
            const float ti = tw.x * b.y + tw.y * b.x;
            W2[lpad(i0)] = make_float2(a.x + tr, a.y + ti);
            W2[lpad(i1)] = make_float2(a.x - tr, a.y - ti);
        }
        __syncthreads();
    }

    const float invM = 1.0f / (float)kM;
    float2* out2 = (float2*)(out + (size_t)h * kL);
    for (int n = tid; n < kM; n += kFftThreads) {
        const float2 zn = W2[lpad(n)];
        out2[n] = make_float2(zn.x * invM, zn.y * invM);
    }
}

extern "C" void kernel_launch(void* const* d_in, const int* in_sizes, int n_in,
                              void* d_out, int out_size, void* d_ws, size_t ws_size,
                              hipStream_t stream) {
    const float* A_real = (const float*)d_in[0];
    const float* A_imag = (const float*)d_in[1];
    const float* B      = (const float*)d_in[2];
    const float* C      = (const float*)d_in[3];
    const float* P      = (const float*)d_in[4];
    const float* inv_dt = (const float*)d_in[5];
    float* out = (float*)d_out;

    s4_spectrum<<<dim3(kH * 2), dim3(kThreads), 0, stream>>>(
        A_real, A_imag, B, C, P, inv_dt, (float2*)out);
    s4_ifft<<<dim3(kH), dim3(kFftThreads), 0, stream>>>(B, C, inv_dt, out);
}